// Round 14
// baseline (80.913 us; speedup 1.0000x reference)
//
#include <hip/hip_runtime.h>

#define IMG_W 1024
#define IMG_H 1024

typedef float f32x4 __attribute__((ext_vector_type(4)));

// ---------------- Kernel A: histogram + clip + scan -> cdf_ws -------------
// One block (256 threads, 4 waves) per tile; 2048 blocks = 8/CU (32 waves/CU).
// Pure read-stream + LDS atomics; writes only 1 KB cdf per tile.
__global__ __launch_bounds__(256, 8) void hist_kernel(const float* __restrict__ img,
                                                      float* __restrict__ cdf_ws) {
    const int tile = blockIdx.x;          // 0..2047
    const int b  = tile >> 6;
    const int ty = (tile >> 3) & 7;
    const int tx = tile & 7;
    const size_t base = ((size_t)b * IMG_H + (size_t)ty * 128) * IMG_W + (size_t)tx * 128;

    const int t = threadIdx.x;            // 0..255
    const int w = t >> 6;                 // wave 0..3

    __shared__ int   hist[4][256];
    __shared__ float exw[4];
    __shared__ float wsum[4];

    hist[0][t] = 0; hist[1][t] = 0; hist[2][t] = 0; hist[3][t] = 0;
    __syncthreads();

    // row = (t>>5) + 8*i, col = (t&31)*4
    const float* p = img + base + (size_t)(t >> 5) * IMG_W + ((t & 31) << 2);

    f32x4 va[4], vb[4];
    #pragma unroll
    for (int j = 0; j < 4; ++j)
        va[j] = *reinterpret_cast<const f32x4*>(p + (size_t)j * 8 * IMG_W);
    #pragma unroll
    for (int g = 0; g < 4; ++g) {
        if (g < 3) {
            #pragma unroll
            for (int j = 0; j < 4; ++j)
                vb[j] = *reinterpret_cast<const f32x4*>(p + (size_t)((g + 1) * 4 + j) * 8 * IMG_W);
        }
        #pragma unroll
        for (int j = 0; j < 4; ++j) {
            const f32x4 v = va[j];
            atomicAdd(&hist[w][min(255, (int)(v.x * 256.0f))], 1);
            atomicAdd(&hist[w][min(255, (int)(v.y * 256.0f))], 1);
            atomicAdd(&hist[w][min(255, (int)(v.z * 256.0f))], 1);
            atomicAdd(&hist[w][min(255, (int)(v.w * 256.0f))], 1);
        }
        if (g < 3) {
            #pragma unroll
            for (int j = 0; j < 4; ++j) va[j] = vb[j];
        }
    }
    __syncthreads();

    // clip + scan (validated R1/R6 math, absmax 0)
    const int h = hist[0][t] + hist[1][t] + hist[2][t] + hist[3][t];

    float ex = (float)max(h - 128, 0);
    #pragma unroll
    for (int off = 32; off > 0; off >>= 1) ex += __shfl_xor(ex, off);
    if ((t & 63) == 0) exw[w] = ex;

    float x = fminf((float)h, 128.0f);
    #pragma unroll
    for (int off = 1; off < 64; off <<= 1) {
        const float y = __shfl_up(x, off);
        if ((t & 63) >= off) x += y;
    }
    if ((t & 63) == 63) wsum[w] = x;
    __syncthreads();

    const float excess = exw[0] + exw[1] + exw[2] + exw[3];
    float prefix = 0.0f;
    if (w > 0) prefix += wsum[0];
    if (w > 1) prefix += wsum[1];
    if (w > 2) prefix += wsum[2];
    const float summinh = wsum[0] + wsum[1] + wsum[2] + wsum[3];
    const float e256 = excess * (1.0f / 256.0f);
    const float total = summinh + excess;
    cdf_ws[(size_t)tile * 256 + t] = (x + prefix + (float)(t + 1) * e256) / total;
}

// ---------------- Kernel B: map via cdf lookup -----------------------------
// One block (256 threads) per tile. Input re-read is L3-resident (R1 evidence:
// second full read added ~0 FETCH). Pure write-stream + LDS gather.
__global__ __launch_bounds__(256, 8) void map_kernel(const float* __restrict__ img,
                                                     const float* __restrict__ cdf_ws,
                                                     float* __restrict__ out) {
    const int tile = blockIdx.x;          // 0..2047
    const int b  = tile >> 6;
    const int ty = (tile >> 3) & 7;
    const int tx = tile & 7;
    const size_t base = ((size_t)b * IMG_H + (size_t)ty * 128) * IMG_W + (size_t)tx * 128;

    const int t = threadIdx.x;            // 0..255

    __shared__ float cdf[256];
    cdf[t] = cdf_ws[(size_t)tile * 256 + t];
    __syncthreads();

    const size_t toff = (size_t)(t >> 5) * IMG_W + ((t & 31) << 2);
    const float* p = img + base + toff;
    float* d = out + base + toff;

    f32x4 va[4], vb[4];
    #pragma unroll
    for (int j = 0; j < 4; ++j)
        va[j] = *reinterpret_cast<const f32x4*>(p + (size_t)j * 8 * IMG_W);
    #pragma unroll
    for (int g = 0; g < 4; ++g) {
        if (g < 3) {
            #pragma unroll
            for (int j = 0; j < 4; ++j)
                vb[j] = *reinterpret_cast<const f32x4*>(p + (size_t)((g + 1) * 4 + j) * 8 * IMG_W);
        }
        #pragma unroll
        for (int j = 0; j < 4; ++j) {
            const f32x4 v = va[j];
            f32x4 o;
            o.x = cdf[min(255, (int)(v.x * 255.0f))];
            o.y = cdf[min(255, (int)(v.y * 255.0f))];
            o.z = cdf[min(255, (int)(v.z * 255.0f))];
            o.w = cdf[min(255, (int)(v.w * 255.0f))];
            __builtin_nontemporal_store(
                o, reinterpret_cast<f32x4*>(d + (size_t)(g * 4 + j) * 8 * IMG_W));
        }
        if (g < 3) {
            #pragma unroll
            for (int j = 0; j < 4; ++j) va[j] = vb[j];
        }
    }
}

extern "C" void kernel_launch(void* const* d_in, const int* in_sizes, int n_in,
                              void* d_out, int out_size, void* d_ws, size_t ws_size,
                              hipStream_t stream) {
    const float* img = (const float*)d_in[0];
    float* out = (float*)d_out;
    float* cdf_ws = (float*)d_ws;         // 2048 * 256 * 4 B = 2 MB
    hist_kernel<<<2048, 256, 0, stream>>>(img, cdf_ws);
    map_kernel<<<2048, 256, 0, stream>>>(img, cdf_ws, out);
}

// Round 15
// 44.208 us; speedup vs baseline: 1.8303x; 1.8303x over previous
//
#include <hip/hip_runtime.h>

#define IMG_W 1024
#define IMG_H 1024

typedef float f32x4 __attribute__((ext_vector_type(4)));

// lgkm-only barrier: drains LDS ops (the only cross-wave dependency) but lets
// NT stores stay in flight across the barrier (R12: neutral vs __syncthreads,
// kept because it is never worse and semantically sufficient here).
__device__ __forceinline__ void lgkm_barrier() {
    asm volatile("s_waitcnt lgkmcnt(0)" ::: "memory");
    __builtin_amdgcn_s_barrier();
    __builtin_amdgcn_sched_barrier(0);
}

// One block (512 threads, 8 waves) per QUAD of horizontally-adjacent 128x128
// tiles. 512 blocks = 2 blocks/CU (16 waves/CU). 4-stage software pipeline:
// store(i-1) overlaps read(i); only first read and last store are exposed.
// Policy validated over 14 rounds: plain loads (input half-rides L3 -> 65 MB
// fetch), NT stores (output bypasses L3, doesn't evict input). Best: 44.2 us.
__global__ __launch_bounds__(512, 4) void clahe_kernel(const float* __restrict__ img,
                                                       float* __restrict__ out) {
    const int quad = blockIdx.x;          // 0..511
    const int t0 = quad << 2;             // first tile of the quad
    const int b  = t0 >> 6;
    const int ty = (t0 >> 3) & 7;
    const int tx = t0 & 7;                // 0 or 4

    const size_t base0 = ((size_t)b * IMG_H + (size_t)ty * 128) * IMG_W + (size_t)tx * 128;

    const int t = threadIdx.x;            // 0..511
    const int w = t >> 6;                 // wave id 0..7

    __shared__ int   hist[8][256];        // 8 KB
    __shared__ float cdf[2][256];         // 2 KB ping-pong
    __shared__ float exw[4];
    __shared__ float wsum[4];

    int* hflat = &hist[0][0];
    hflat[t] = 0; hflat[t + 512] = 0; hflat[t + 1024] = 0; hflat[t + 1536] = 0;
    lgkm_barrier();

    // thread's element j of a tile: row = (t>>5) + 16*j, col = (t&31)*4
    const size_t toff = (size_t)(t >> 5) * IMG_W + ((t & 31) << 2);
    const float* __restrict__ p0 = img + base0 + toff;
    float* __restrict__ d0 = out + base0 + toff;

    unsigned int pk[2][8];                // ping-pong packed 255-indices
    f32x4 v[8];

    auto binpack = [&](const f32x4 vv, unsigned int* pkp) {
        atomicAdd(&hist[w][min(255, (int)(vv.x * 256.0f))], 1);
        atomicAdd(&hist[w][min(255, (int)(vv.y * 256.0f))], 1);
        atomicAdd(&hist[w][min(255, (int)(vv.z * 256.0f))], 1);
        atomicAdd(&hist[w][min(255, (int)(vv.w * 256.0f))], 1);
        *pkp = (unsigned int)min(255, (int)(vv.x * 255.0f))
             | ((unsigned int)min(255, (int)(vv.y * 255.0f)) << 8)
             | ((unsigned int)min(255, (int)(vv.z * 255.0f)) << 16)
             | ((unsigned int)min(255, (int)(vv.w * 255.0f)) << 24);
    };

    // clip + scan -> cdf[s]; zeroes hist for the next tile. One internal
    // lgkm-barrier; caller barriers after before consuming cdf[s].
    auto scan_fn = [&](int s) {
        int h = 0;
        float x = 0.0f;
        if (t < 256) {
            h = hist[0][t] + hist[1][t] + hist[2][t] + hist[3][t]
              + hist[4][t] + hist[5][t] + hist[6][t] + hist[7][t];

            float ex = (float)max(h - 128, 0);
            #pragma unroll
            for (int off = 32; off > 0; off >>= 1) ex += __shfl_xor(ex, off);
            if ((t & 63) == 0) exw[w] = ex;

            x = fminf((float)h, 128.0f);
            #pragma unroll
            for (int off = 1; off < 64; off <<= 1) {
                const float y = __shfl_up(x, off);
                if ((t & 63) >= off) x += y;
            }
            if ((t & 63) == 63) wsum[w] = x;
        }
        lgkm_barrier();
        // zero hist for next tile (reads of hist completed above)
        hflat[t] = 0; hflat[t + 512] = 0; hflat[t + 1024] = 0; hflat[t + 1536] = 0;
        if (t < 256) {
            const float excess = exw[0] + exw[1] + exw[2] + exw[3];
            float prefix = 0.0f;
            if (w > 0) prefix += wsum[0];
            if (w > 1) prefix += wsum[1];
            if (w > 2) prefix += wsum[2];
            const float summinh = wsum[0] + wsum[1] + wsum[2] + wsum[3];
            const float e256 = excess * (1.0f / 256.0f);
            const float total = summinh + excess;
            cdf[s][t] = (x + prefix + (float)(t + 1) * e256) / total;
        }
    };

    #pragma unroll
    for (int i = 0; i < 4; ++i) {
        const float* pi = p0 + (size_t)i * 128;
        // issue this tile's 8 loads first (MLP), then overlap prev-tile store
        #pragma unroll
        for (int j = 0; j < 8; ++j)
            v[j] = *reinterpret_cast<const f32x4*>(pi + (size_t)j * 16 * IMG_W);

        if (i > 0) {
            float* dprev = d0 + (size_t)(i - 1) * 128;
            #pragma unroll
            for (int j = 0; j < 8; ++j) {
                const unsigned int u = pk[(i - 1) & 1][j];
                f32x4 o;
                o.x = cdf[(i - 1) & 1][u & 255u];
                o.y = cdf[(i - 1) & 1][(u >> 8) & 255u];
                o.z = cdf[(i - 1) & 1][(u >> 16) & 255u];
                o.w = cdf[(i - 1) & 1][u >> 24];
                __builtin_nontemporal_store(
                    o, reinterpret_cast<f32x4*>(dprev + (size_t)j * 16 * IMG_W));
            }
        }

        #pragma unroll
        for (int j = 0; j < 8; ++j) binpack(v[j], &pk[i & 1][j]);
        lgkm_barrier();

        scan_fn(i & 1);
        lgkm_barrier();
    }

    // epilogue: store tile 3
    {
        float* dprev = d0 + (size_t)3 * 128;
        #pragma unroll
        for (int j = 0; j < 8; ++j) {
            const unsigned int u = pk[1][j];
            f32x4 o;
            o.x = cdf[1][u & 255u];
            o.y = cdf[1][(u >> 8) & 255u];
            o.z = cdf[1][(u >> 16) & 255u];
            o.w = cdf[1][u >> 24];
            __builtin_nontemporal_store(
                o, reinterpret_cast<f32x4*>(dprev + (size_t)j * 16 * IMG_W));
        }
    }
}

extern "C" void kernel_launch(void* const* d_in, const int* in_sizes, int n_in,
                              void* d_out, int out_size, void* d_ws, size_t ws_size,
                              hipStream_t stream) {
    const float* img = (const float*)d_in[0];
    float* out = (float*)d_out;
    clahe_kernel<<<512, 512, 0, stream>>>(img, out);
}